// Round 7
// baseline (61.554 us; speedup 1.0000x reference)
//
#include <hip/hip_runtime.h>

#define BB 8
#define HH 64
#define WW 2048
#define NC 20

// tile: 4 rows x 64 cols per 256-thread block
// depth halo = 4 (9x9 reach, 0.0-padded = exact reference unfold zero-pad:
//   |0 - Dq| = Dq, identical to the reference's padded-neighbor jump)
// label halo = 2 (5x5 reach, 0-padded)
//
// Evidence ledger:
//  R1: 4op/term, VGPR=48, 65us | R4: 2op/term reg-resident, VGPR=108, 68us
//  R5: VGPR cap -> 290MB scratch, 112us | R6: runtime-jy loop, VGPR=48, 61us
//  R7 = R6 + bit-exact overhead cuts:
//   (a) k=12 shortcut: dist[12]==+0.0 is the guaranteed first top-k pick
//       (cutoff 0<=1 -> own label); rounds 1-4 scan 24 elems.
//   (b) block-uniform interior path: weights read raw from LDS (no mask muls).
//   (c) canonical |diff| operand order -> GVN CSEs paired subs (same-row pairs).

__global__ void knn_refine(
    const float* __restrict__ depth,
    const int*   __restrict__ label,
    const float* __restrict__ wker,
    int*         __restrict__ out)
{
    __shared__ float sD[12][72];
    __shared__ int   sL[8][68];
    __shared__ float sW[25];

    const int b  = blockIdx.z;
    const int y0 = blockIdx.y * 4;
    const int x0 = blockIdx.x * 64;
    const int t  = threadIdx.x;

    const float* Db = depth + (size_t)b * (HH * WW);
    const int*   Lb = label + (size_t)b * (HH * WW);

    // ---- stage depth tile (+4 halo), OOB pad = 0.0 ----
    for (int idx = t; idx < 12 * 72; idx += 256) {
        int ry = idx / 72, rx = idx - ry * 72;
        int gyy = y0 + ry - 4, gxx = x0 + rx - 4;
        float v = 0.0f;
        if (gyy >= 0 && gyy < HH && gxx >= 0 && gxx < WW) v = Db[gyy * WW + gxx];
        sD[ry][rx] = v;
    }
    // ---- stage label tile (+2 halo), OOB pad = 0 ----
    for (int idx = t; idx < 8 * 68; idx += 256) {
        int ry = idx / 68, rx = idx - ry * 68;
        int gyy = y0 + ry - 2, gxx = x0 + rx - 2;
        int v = 0;
        if (gyy >= 0 && gyy < HH && gxx >= 0 && gxx < WW) v = Lb[gyy * WW + gxx];
        sL[ry][rx] = v;
    }
    // ---- stage weights (uniform-address broadcast reads later) ----
    if (t < 25) sW[t] = wker[t];
    __syncthreads();

    const int px = t & 63;
    const int py = t >> 6;
    const int gy = y0 + py;
    const int gx = x0 + px;

    // block-uniform: does any pixel of this block have an OOB anchor?
    const bool edgeBlock = (y0 == 0) | (y0 == HH - 4) | (x0 == 0) | (x0 == WW - 64);

    // x-direction anchor masks (exact 0/1), used only on the edge path
    float mx[5];
#pragma unroll
    for (int d = 0; d < 5; ++d)
        mx[d] = ((unsigned)(gx + d - 2) < (unsigned)WW) ? 1.0f : 0.0f;

    float dist[25];
#pragma unroll
    for (int k = 0; k < 25; ++k) dist[k] = 0.0f;
    // dist[12] stays exactly +0.0 (k-offset (0,0)): skipped in accumulation.

    // ---- main loop: jy RUNTIME (no unroll) -> bounded live set, no spills ----
#pragma clang loop unroll(disable)
    for (int jy = 0; jy < 5; ++jy) {
        const float* rp = &sD[py + jy][px];   // runtime base, static offsets
        float row[5][9];                       // statically indexed only
#pragma unroll
        for (int r = 0; r < 5; ++r)
#pragma unroll
            for (int c = 0; c < 9; ++c)
                row[r][c] = rp[r * 72 + c];

        float wrow[5];
        if (!edgeBlock) {
#pragma unroll
            for (int jx = 0; jx < 5; ++jx)
                wrow[jx] = sW[jy * 5 + jx];                    // no mask math
        } else {
            const float myy = ((unsigned)(gy + jy - 2) < (unsigned)HH) ? 1.0f : 0.0f;
#pragma unroll
            for (int jx = 0; jx < 5; ++jx)
                wrow[jx] = myy * mx[jx] * sW[jy * 5 + jx];     // exact *1.0/0.0
        }

#pragma unroll
        for (int jx = 0; jx < 5; ++jx) {
            const float Dq = row[2][jx + 2];
            const float wj = wrow[jx];
#pragma unroll
            for (int k = 0; k < 25; ++k) {
                if (k == 12) continue;
                const int ky = k / 5, kx = k % 5;
                const int nlin = ky * 9 + jx + kx;     // window linear pos
                const int alin = 2 * 9 + jx + 2;       // anchor linear pos
                // canonical operand order: |x-y| == |y-x| bit-exactly, and
                // fixed ordering lets GVN CSE the sub shared by paired terms
                float diff;
                if (nlin > alin) diff = row[ky][jx + kx] - Dq;
                else             diff = Dq - row[ky][jx + kx];
                dist[k] = fmaf(wj, fabsf(diff), dist[k]);
            }
        }
    }

    // ---- top-5 smallest. Round 0 is always k=12 (dist==+0.0, cutoff 0<=1):
    //      own pixel's label. Rounds 1-4: strict-< scan, ties -> lower k. ----
    int labs[5];
    labs[0] = sL[py + 2][px + 2];
#pragma unroll
    for (int r = 1; r < 5; ++r) {
        float best = 3.4e38f;
        int bi = 0;
#pragma unroll
        for (int k = 0; k < 25; ++k) {
            if (k == 12) continue;
            if (dist[k] < best) { best = dist[k]; bi = k; }
        }
        int ky = (bi * 205) >> 10;            // bi / 5 for bi in [0,25)
        int kx = bi - ky * 5;
        labs[r] = (best > 1.0f) ? NC : sL[py + ky][px + kx];
        if (r < 4) {
#pragma unroll
            for (int k = 0; k < 25; ++k) {
                if (k == 12) continue;
                if (k == bi) dist[k] = 3.4e38f;
            }
        }
    }

    // ---- majority vote over 5 labels; argmax ties -> lowest class index ----
    int bestLab = 0, bestCnt = 0;
#pragma unroll
    for (int i = 0; i < 5; ++i) {
        const int li = labs[i];
        int c = 0;
#pragma unroll
        for (int j = 0; j < 5; ++j) c += (labs[j] == li) ? 1 : 0;
        if (li < NC && (c > bestCnt || (c == bestCnt && li < bestLab))) {
            bestCnt = c;
            bestLab = li;
        }
    }

    out[(size_t)b * (HH * WW) + (size_t)gy * WW + gx] = bestLab;
}

extern "C" void kernel_launch(void* const* d_in, const int* in_sizes, int n_in,
                              void* d_out, int out_size, void* d_ws, size_t ws_size,
                              hipStream_t stream) {
    const float* depth = (const float*)d_in[0];
    const int*   label = (const int*)d_in[1];
    const float* wker  = (const float*)d_in[2];
    int*         out   = (int*)d_out;

    dim3 grid(WW / 64, HH / 4, BB);
    knn_refine<<<grid, dim3(256), 0, stream>>>(depth, label, wker, out);
}

// Round 8
// 58.507 us; speedup vs baseline: 1.0521x; 1.0521x over previous
//
#include <hip/hip_runtime.h>

#define BB 8
#define HH 64
#define WW 2048
#define HW (HH * WW)
#define NC 20
#define TPB 256

// 4x64 tile per compute step; 2 tiles per persistent block, double-buffered.
// Tiles: 32(tx) x 16(ty) x 8(b) = 4096; grid = 2048 blocks = 8 blocks/CU
// pinned co-resident (VGPR<=64, LDS 11.5KB).
//
// Evidence ledger: R1 625LDS/2700VALU=65us | R4 81LDS/108VGPR=68us |
// R6 225LDS/48VGPR=61us | R7 op-cuts=neutral. Instruction count is NOT the
// limiter; achieved occupancy stuck at 0.42x theoretical in all rounds =>
// stall/residency bound (per-block HBM stage latency + dispatch churn).
// R8: persistent blocks, prefetch next tile into regs during compute (T14).

__device__ __forceinline__ void tile_coords(int tid, int& bb, int& y0, int& x0) {
    int tx = tid & 31;          // x fastest: consecutive tiles share halo cols
    int r  = tid >> 5;
    int ty = r & 15;
    bb = r >> 4;
    y0 = ty * 4;
    x0 = tx * 64;
}

__device__ __forceinline__ void stage_load(const float* __restrict__ depth,
                                           const int* __restrict__ label,
                                           int tid, int t,
                                           float dreg[4], int lreg[3]) {
    int bb, y0, x0;
    tile_coords(tid, bb, y0, x0);
    const float* Db = depth + (size_t)bb * HW;
    const int*   Lb = label + (size_t)bb * HW;
#pragma unroll
    for (int i = 0; i < 4; ++i) {
        int idx = t + i * TPB;
        float v = 0.0f;
        if (idx < 12 * 72) {
            int ry = idx / 72, rx = idx - ry * 72;
            int gy = y0 + ry - 4, gx = x0 + rx - 4;
            if ((unsigned)gy < (unsigned)HH && (unsigned)gx < (unsigned)WW)
                v = Db[gy * WW + gx];
        }
        dreg[i] = v;
    }
#pragma unroll
    for (int i = 0; i < 3; ++i) {
        int idx = t + i * TPB;
        int v = 0;
        if (idx < 8 * 68) {
            int ry = idx / 68, rx = idx - ry * 68;
            int gy = y0 + ry - 2, gx = x0 + rx - 2;
            if ((unsigned)gy < (unsigned)HH && (unsigned)gx < (unsigned)WW)
                v = Lb[gy * WW + gx];
        }
        lreg[i] = v;
    }
}

__device__ __forceinline__ void stage_write(float (*sD)[72], int (*sL)[68],
                                            int t, const float dreg[4],
                                            const int lreg[3]) {
#pragma unroll
    for (int i = 0; i < 4; ++i) {
        int idx = t + i * TPB;
        if (idx < 12 * 72) (&sD[0][0])[idx] = dreg[i];
    }
#pragma unroll
    for (int i = 0; i < 3; ++i) {
        int idx = t + i * TPB;
        if (idx < 8 * 68) (&sL[0][0])[idx] = lreg[i];
    }
}

__device__ __forceinline__ void compute_tile(const float (*sDt)[72],
                                             const int (*sLt)[68],
                                             const float* sW,
                                             int tid, int t,
                                             int* __restrict__ out) {
    int bb, y0, x0;
    tile_coords(tid, bb, y0, x0);
    const int px = t & 63;
    const int py = t >> 6;
    const int gy = y0 + py;
    const int gx = x0 + px;

    // anchor-OOB masks (exact 0/1 floats): conv zero-pads jump in p-space
    float mx[5];
#pragma unroll
    for (int d = 0; d < 5; ++d)
        mx[d] = ((unsigned)(gx + d - 2) < (unsigned)WW) ? 1.0f : 0.0f;

    float dist[25];
#pragma unroll
    for (int k = 0; k < 25; ++k) dist[k] = 0.0f;
    // dist[12] (k-offset (0,0)) stays exactly +0.0: skipped in accumulation.

    // jy RUNTIME loop (no unroll) -> bounded live set, no spills (R6 lesson)
#pragma clang loop unroll(disable)
    for (int jy = 0; jy < 5; ++jy) {
        const float* rp = &sDt[py + jy][px];
        float row[5][9];                       // statically indexed only
#pragma unroll
        for (int r = 0; r < 5; ++r)
#pragma unroll
            for (int c = 0; c < 9; ++c)
                row[r][c] = rp[r * 72 + c];

        const float myy = ((unsigned)(gy + jy - 2) < (unsigned)HH) ? 1.0f : 0.0f;

#pragma unroll
        for (int jx = 0; jx < 5; ++jx) {
            const float wj = myy * mx[jx] * sW[jy * 5 + jx];  // exact *1/0
            const float Dq = row[2][jx + 2];
#pragma unroll
            for (int k = 0; k < 25; ++k) {
                if (k == 12) continue;
                const int ky = k / 5, kx = k % 5;
                const int nlin = ky * 9 + jx + kx;
                const int alin = 2 * 9 + jx + 2;
                // canonical operand order: |x-y|==|y-x| bit-exact, enables CSE
                float diff;
                if (nlin > alin) diff = row[ky][jx + kx] - Dq;
                else             diff = Dq - row[ky][jx + kx];
                dist[k] = fmaf(wj, fabsf(diff), dist[k]);
            }
        }
    }

    // top-5 smallest. Round 0 is always k=12 (dist==+0.0, cutoff 0<=1):
    // own pixel's label. Rounds 1-4: strict-< scan, ties -> lower k.
    int labs[5];
    labs[0] = sLt[py + 2][px + 2];
#pragma unroll
    for (int r = 1; r < 5; ++r) {
        float best = 3.4e38f;
        int bi = 0;
#pragma unroll
        for (int k = 0; k < 25; ++k) {
            if (k == 12) continue;
            if (dist[k] < best) { best = dist[k]; bi = k; }
        }
        int ky = (bi * 205) >> 10;            // bi / 5 for bi in [0,25)
        int kx = bi - ky * 5;
        labs[r] = (best > 1.0f) ? NC : sLt[py + ky][px + kx];
        if (r < 4) {
#pragma unroll
            for (int k = 0; k < 25; ++k) {
                if (k == 12) continue;
                if (k == bi) dist[k] = 3.4e38f;
            }
        }
    }

    // majority vote; argmax ties -> lowest class index
    int bestLab = 0, bestCnt = 0;
#pragma unroll
    for (int i = 0; i < 5; ++i) {
        const int li = labs[i];
        int c = 0;
#pragma unroll
        for (int j = 0; j < 5; ++j) c += (labs[j] == li) ? 1 : 0;
        if (li < NC && (c > bestCnt || (c == bestCnt && li < bestLab))) {
            bestCnt = c;
            bestLab = li;
        }
    }

    out[(size_t)bb * HW + (size_t)gy * WW + gx] = bestLab;
}

__global__ __launch_bounds__(TPB) void knn_refine(
    const float* __restrict__ depth,
    const int*   __restrict__ label,
    const float* __restrict__ wker,
    int*         __restrict__ out)
{
    __shared__ float sD[2][12][72];
    __shared__ int   sL[2][8][68];
    __shared__ float sW[25];

    const int t    = threadIdx.x;
    const int tid0 = blockIdx.x * 2;          // 2 tiles per persistent block

    float dreg[4];
    int   lreg[3];

    // prologue: stage tile 0 into buffer 0
    stage_load(depth, label, tid0, t, dreg, lreg);
    if (t < 25) sW[t] = wker[t];
    stage_write(sD[0], sL[0], t, dreg, lreg);
    __syncthreads();

    // tile 0: issue tile-1 loads FIRST (hidden under ~10us of compute),
    // then compute, then park loads into buffer 1.
    stage_load(depth, label, tid0 + 1, t, dreg, lreg);
    compute_tile(sD[0], sL[0], sW, tid0, t, out);
    stage_write(sD[1], sL[1], t, dreg, lreg);
    __syncthreads();

    // tile 1
    compute_tile(sD[1], sL[1], sW, tid0 + 1, t, out);
}

extern "C" void kernel_launch(void* const* d_in, const int* in_sizes, int n_in,
                              void* d_out, int out_size, void* d_ws, size_t ws_size,
                              hipStream_t stream) {
    const float* depth = (const float*)d_in[0];
    const int*   label = (const int*)d_in[1];
    const float* wker  = (const float*)d_in[2];
    int*         out   = (int*)d_out;

    knn_refine<<<dim3(2048), dim3(TPB), 0, stream>>>(depth, label, wker, out);
}

// Round 9
// 31.399 us; speedup vs baseline: 1.9604x; 1.8634x over previous
//
#include <hip/hip_runtime.h>

#define BB 8
#define HH 64
#define WW 2048
#define HW (HH * WW)
#define NC 20
#define TPB 256

// 4x64 tile per compute step; 2 tiles per persistent block, double-buffered.
// Evidence ledger: R6-R8 all ~58-61us, co-bound: ~225 ds_read_b32/px (~35us
// LDS pipe @5.8cyc) + ~24us VALU, poorly overlapped. R9 adds an EXACT
// monotone early-exit: dist[k] is a nondecreasing partial sum; if after the
// jy=0 row all 24 non-self dists exceed CUTOFF=1.0, the final vote is
// provably {self, NC,NC,NC,NC} -> own label. Wave-uniform (__all), exact
// fallback otherwise. On uniform[0,80) depth the slow path is ~never taken
// => ~4x less LDS traffic and ~5x less VALU per pixel.

__device__ __forceinline__ void tile_coords(int tid, int& bb, int& y0, int& x0) {
    int tx = tid & 31;          // x fastest: consecutive tiles share halo cols
    int r  = tid >> 5;
    int ty = r & 15;
    bb = r >> 4;
    y0 = ty * 4;
    x0 = tx * 64;
}

__device__ __forceinline__ void stage_load(const float* __restrict__ depth,
                                           const int* __restrict__ label,
                                           int tid, int t,
                                           float dreg[4], int lreg[3]) {
    int bb, y0, x0;
    tile_coords(tid, bb, y0, x0);
    const float* Db = depth + (size_t)bb * HW;
    const int*   Lb = label + (size_t)bb * HW;
#pragma unroll
    for (int i = 0; i < 4; ++i) {
        int idx = t + i * TPB;
        float v = 0.0f;
        if (idx < 12 * 72) {
            int ry = idx / 72, rx = idx - ry * 72;
            int gy = y0 + ry - 4, gx = x0 + rx - 4;
            if ((unsigned)gy < (unsigned)HH && (unsigned)gx < (unsigned)WW)
                v = Db[gy * WW + gx];
        }
        dreg[i] = v;
    }
#pragma unroll
    for (int i = 0; i < 3; ++i) {
        int idx = t + i * TPB;
        int v = 0;
        if (idx < 8 * 68) {
            int ry = idx / 68, rx = idx - ry * 68;
            int gy = y0 + ry - 2, gx = x0 + rx - 2;
            if ((unsigned)gy < (unsigned)HH && (unsigned)gx < (unsigned)WW)
                v = Lb[gy * WW + gx];
        }
        lreg[i] = v;
    }
}

__device__ __forceinline__ void stage_write(float (*sD)[72], int (*sL)[68],
                                            int t, const float dreg[4],
                                            const int lreg[3]) {
#pragma unroll
    for (int i = 0; i < 4; ++i) {
        int idx = t + i * TPB;
        if (idx < 12 * 72) (&sD[0][0])[idx] = dreg[i];
    }
#pragma unroll
    for (int i = 0; i < 3; ++i) {
        int idx = t + i * TPB;
        if (idx < 8 * 68) (&sL[0][0])[idx] = lreg[i];
    }
}

// one jy row of the accumulation; bit-exact chain order (jy outer, jx inner)
__device__ __forceinline__ void accum_row(const float (*sDt)[72],
                                          const float* sW,
                                          int py, int px, int gy,
                                          const float mx[5], int jy,
                                          float dist[25]) {
    const float* rp = &sDt[py + jy][px];   // runtime base, static offsets
    float row[5][9];                        // statically indexed only
#pragma unroll
    for (int r = 0; r < 5; ++r)
#pragma unroll
        for (int c = 0; c < 9; ++c)
            row[r][c] = rp[r * 72 + c];

    const float myy = ((unsigned)(gy + jy - 2) < (unsigned)HH) ? 1.0f : 0.0f;

#pragma unroll
    for (int jx = 0; jx < 5; ++jx) {
        const float wj = myy * mx[jx] * sW[jy * 5 + jx];  // exact *1.0/0.0
        const float Dq = row[2][jx + 2];
#pragma unroll
        for (int k = 0; k < 25; ++k) {
            if (k == 12) continue;
            const int ky = k / 5, kx = k % 5;
            const int nlin = ky * 9 + jx + kx;
            const int alin = 2 * 9 + jx + 2;
            // canonical operand order: |x-y|==|y-x| bit-exact, enables CSE
            float diff;
            if (nlin > alin) diff = row[ky][jx + kx] - Dq;
            else             diff = Dq - row[ky][jx + kx];
            dist[k] = fmaf(wj, fabsf(diff), dist[k]);
        }
    }
}

__device__ __forceinline__ void compute_tile(const float (*sDt)[72],
                                             const int (*sLt)[68],
                                             const float* sW,
                                             int tid, int t,
                                             int* __restrict__ out) {
    int bb, y0, x0;
    tile_coords(tid, bb, y0, x0);
    const int px = t & 63;
    const int py = t >> 6;
    const int gy = y0 + py;
    const int gx = x0 + px;
    int* const op = &out[(size_t)bb * HW + (size_t)gy * WW + gx];

    // anchor-OOB masks (exact 0/1 floats): conv zero-pads jump in p-space
    float mx[5];
#pragma unroll
    for (int d = 0; d < 5; ++d)
        mx[d] = ((unsigned)(gx + d - 2) < (unsigned)WW) ? 1.0f : 0.0f;

    float dist[25];
#pragma unroll
    for (int k = 0; k < 25; ++k) dist[k] = 0.0f;
    // dist[12] (k-offset (0,0)) stays exactly +0.0: skipped in accumulation.

    // ---- jy = 0 row, then exact monotone early-exit vs CUTOFF ----
    accum_row(sDt, sW, py, px, gy, mx, 0, dist);

    float mn = 3.4e38f;
#pragma unroll
    for (int k = 0; k < 25; ++k) {
        if (k == 12) continue;
        mn = fminf(mn, dist[k]);
    }
    // dist[k] only grows; if every non-self dist already exceeds 1.0, the
    // final top-5 is {self, NC,NC,NC,NC} -> majority vote = own label.
    if (__all(mn > 1.0f)) {
        *op = sLt[py + 2][px + 2];
        return;
    }

    // ---- exact slow path: remaining rows (runtime loop, R6 lesson) ----
#pragma clang loop unroll(disable)
    for (int jy = 1; jy < 5; ++jy)
        accum_row(sDt, sW, py, px, gy, mx, jy, dist);

    // top-5 smallest. Round 0 is always k=12 (dist==+0.0, cutoff 0<=1):
    // own pixel's label. Rounds 1-4: strict-< scan, ties -> lower k.
    int labs[5];
    labs[0] = sLt[py + 2][px + 2];
#pragma unroll
    for (int r = 1; r < 5; ++r) {
        float best = 3.4e38f;
        int bi = 0;
#pragma unroll
        for (int k = 0; k < 25; ++k) {
            if (k == 12) continue;
            if (dist[k] < best) { best = dist[k]; bi = k; }
        }
        int ky = (bi * 205) >> 10;            // bi / 5 for bi in [0,25)
        int kx = bi - ky * 5;
        labs[r] = (best > 1.0f) ? NC : sLt[py + ky][px + kx];
        if (r < 4) {
#pragma unroll
            for (int k = 0; k < 25; ++k) {
                if (k == 12) continue;
                if (k == bi) dist[k] = 3.4e38f;
            }
        }
    }

    // majority vote; argmax ties -> lowest class index
    int bestLab = 0, bestCnt = 0;
#pragma unroll
    for (int i = 0; i < 5; ++i) {
        const int li = labs[i];
        int c = 0;
#pragma unroll
        for (int j = 0; j < 5; ++j) c += (labs[j] == li) ? 1 : 0;
        if (li < NC && (c > bestCnt || (c == bestCnt && li < bestLab))) {
            bestCnt = c;
            bestLab = li;
        }
    }

    *op = bestLab;
}

__global__ __launch_bounds__(TPB) void knn_refine(
    const float* __restrict__ depth,
    const int*   __restrict__ label,
    const float* __restrict__ wker,
    int*         __restrict__ out)
{
    __shared__ float sD[2][12][72];
    __shared__ int   sL[2][8][68];
    __shared__ float sW[25];

    const int t    = threadIdx.x;
    const int tid0 = blockIdx.x * 2;          // 2 tiles per persistent block

    float dreg[4];
    int   lreg[3];

    // prologue: stage tile 0 into buffer 0
    stage_load(depth, label, tid0, t, dreg, lreg);
    if (t < 25) sW[t] = wker[t];
    stage_write(sD[0], sL[0], t, dreg, lreg);
    __syncthreads();

    // tile 0: issue tile-1 loads FIRST (hidden under compute), then compute,
    // then park loads into buffer 1.
    stage_load(depth, label, tid0 + 1, t, dreg, lreg);
    compute_tile(sD[0], sL[0], sW, tid0, t, out);
    stage_write(sD[1], sL[1], t, dreg, lreg);
    __syncthreads();

    // tile 1
    compute_tile(sD[1], sL[1], sW, tid0 + 1, t, out);
}

extern "C" void kernel_launch(void* const* d_in, const int* in_sizes, int n_in,
                              void* d_out, int out_size, void* d_ws, size_t ws_size,
                              hipStream_t stream) {
    const float* depth = (const float*)d_in[0];
    const int*   label = (const int*)d_in[1];
    const float* wker  = (const float*)d_in[2];
    int*         out   = (int*)d_out;

    knn_refine<<<dim3(2048), dim3(TPB), 0, stream>>>(depth, label, wker, out);
}